// Round 1
// baseline (314.644 us; speedup 1.0000x reference)
//
#include <hip/hip_runtime.h>
#include <cstdint>
#include <cstddef>

#define B 8
#define L 1024
#define DM 512
#define H 8
#define DK 64
#define DV 64
#define LN_EPS 1e-5f

// workspace layout (float offsets)
#define U_OFF    0        // DM*H = 4096      u[dm*8+h] = Wk[:,h*64:] @ wmap_k
#define CK_OFF   4096     // 8                ck[h]     = bk[h*64:] . wmap_k
#define SK_OFF   8192     // H*B*L = 65536    sk[(h*B+b)*L + l]
#define P_OFF    73728    // H*B*L = 65536    p  (softmax of sk per (h,b) row)
#define VBAR_OFF 139264   // H*B*DM = 32768   vbar[(h*B+b)*DM + dm]
#define CTX_OFF  172032   // B*DM = 4096      ctxcat[b*DM + h*64+d]
#define OB_OFF   176128   // B*DM = 4096      obase[b*DM + n]

#define OUT_ELEMS  ((size_t)B * L * DM)      // 4194304, attn follows

// ---------- Kernel A: fold Wk @ wmap_k into u (DM x H), ck ----------
__global__ __launch_bounds__(512) void k_prep(const float* __restrict__ Wk,
                                              const float* __restrict__ bk,
                                              const float* __restrict__ Wmap,
                                              float* __restrict__ ws) {
    __shared__ float wm[DK];
    int t = threadIdx.x;
    if (t < DK) wm[t] = Wmap[DK + t];
    __syncthreads();
    int dm = t;  // 512 threads, one per dm
    const float* row = Wk + (size_t)dm * (H * DK);
#pragma unroll
    for (int h = 0; h < H; ++h) {
        float s = 0.f;
#pragma unroll 8
        for (int d = 0; d < DK; ++d) s += row[h * DK + d] * wm[d];
        ws[U_OFF + dm * H + h] = s;
    }
    if (t < H) {
        float s = 0.f;
        for (int d = 0; d < DK; ++d) s += bk[t * DK + d] * wm[d];
        ws[CK_OFF + t] = s;
    }
}

// ---------- Kernel B: sk[h,b,l] = k[b,l,:] . u[:,h] + ck[h] ----------
__global__ __launch_bounds__(256) void k_sk(const float* __restrict__ k,
                                            float* __restrict__ ws) {
    int wave = threadIdx.x >> 6, lane = threadIdx.x & 63;
    int row = blockIdx.x * 4 + wave;  // 0..8191 == b*L + l
    int b = row >> 10, l = row & 1023;
    const float* krow = k + (size_t)row * DM;
    const float* u = ws + U_OFF;
    float acc[8] = {0, 0, 0, 0, 0, 0, 0, 0};
#pragma unroll
    for (int s = 0; s < 8; ++s) {
        int dm = s * 64 + lane;
        float kv = krow[dm];
        const float4 ua = *(const float4*)(u + dm * 8);
        const float4 ub = *(const float4*)(u + dm * 8 + 4);
        acc[0] += kv * ua.x; acc[1] += kv * ua.y;
        acc[2] += kv * ua.z; acc[3] += kv * ua.w;
        acc[4] += kv * ub.x; acc[5] += kv * ub.y;
        acc[6] += kv * ub.z; acc[7] += kv * ub.w;
    }
#pragma unroll
    for (int off = 32; off > 0; off >>= 1) {
#pragma unroll
        for (int h = 0; h < 8; ++h) acc[h] += __shfl_xor(acc[h], off, 64);
    }
    float vout = 0.f;  // static-index pick (avoid scratch from runtime reg index)
#pragma unroll
    for (int h = 0; h < 8; ++h) if (lane == h) vout = acc[h];
    if (lane < 8)
        ws[SK_OFF + ((size_t)(lane * B + b)) * L + l] = vout + ws[CK_OFF + lane];
}

// ---------- Kernel C: p = softmax(sk) per (h,b) row of length L ----------
__global__ __launch_bounds__(256) void k_softmax(float* __restrict__ ws) {
    int hb = blockIdx.x, t = threadIdx.x;
    int wave = t >> 6, lane = t & 63;
    const float4 s4 = *(const float4*)&ws[SK_OFF + (size_t)hb * L + t * 4];
    __shared__ float sred[4];
    __shared__ float bc[1];
    float m = fmaxf(fmaxf(s4.x, s4.y), fmaxf(s4.z, s4.w));
#pragma unroll
    for (int off = 32; off > 0; off >>= 1) m = fmaxf(m, __shfl_xor(m, off, 64));
    if (lane == 0) sred[wave] = m;
    __syncthreads();
    if (t == 0) bc[0] = fmaxf(fmaxf(sred[0], sred[1]), fmaxf(sred[2], sred[3]));
    __syncthreads();
    m = bc[0];
    float e0 = expf(s4.x - m), e1 = expf(s4.y - m), e2 = expf(s4.z - m), e3 = expf(s4.w - m);
    float s = e0 + e1 + e2 + e3;
#pragma unroll
    for (int off = 32; off > 0; off >>= 1) s += __shfl_xor(s, off, 64);
    __syncthreads();  // protect sred reuse
    if (lane == 0) sred[wave] = s;
    __syncthreads();
    if (t == 0) bc[0] = sred[0] + sred[1] + sred[2] + sred[3];
    __syncthreads();
    float inv = 1.f / bc[0];
    float4 p4 = {e0 * inv, e1 * inv, e2 * inv, e3 * inv};
    *(float4*)&ws[P_OFF + (size_t)hb * L + t * 4] = p4;
}

// ---------- Kernel C2: vbar[h,b,dm] = sum_j p[h,b,j] * v[b,j,dm] ----------
__global__ __launch_bounds__(512) void k_vbar(const float* __restrict__ v,
                                              float* __restrict__ ws) {
    __shared__ float ps[H * L];  // 32 KB
    int b = blockIdx.x & 7, chunk = blockIdx.x >> 3;
    for (int idx = threadIdx.x; idx < H * L; idx += 512) {
        int h = idx >> 10, j = idx & 1023;
        ps[idx] = ws[P_OFF + ((size_t)(h * B + b)) * L + j];
    }
    __syncthreads();
    int h = threadIdx.x >> 6, dml = threadIdx.x & 63;
    int dm = chunk * 64 + dml;
    const float* vb = v + ((size_t)b * L) * DM + dm;
    const float* ph = &ps[h * L];
    float acc = 0.f;
#pragma unroll 4
    for (int j = 0; j < L; ++j) acc += ph[j] * vb[(size_t)j * DM];
    ws[VBAR_OFF + ((size_t)(h * B + b)) * DM + dm] = acc;
}

// ---------- Kernel D1: ctx[b, h*64+d] = vbar[h,b,:] @ Wv[:, h*64+d] + bv ----------
__global__ __launch_bounds__(64) void k_ctx(const float* __restrict__ Wv,
                                            const float* __restrict__ bv,
                                            float* __restrict__ ws) {
    __shared__ float vb[DM];
    int hb = blockIdx.x;
    int h = hb >> 3, b = hb & 7;
    for (int i = threadIdx.x; i < DM; i += 64)
        vb[i] = ws[VBAR_OFF + (size_t)hb * DM + i];
    __syncthreads();
    int d = threadIdx.x;
    float acc = bv[h * DV + d];
#pragma unroll 4
    for (int dm = 0; dm < DM; ++dm)
        acc += vb[dm] * Wv[(size_t)dm * (H * DV) + h * DV + d];
    ws[CTX_OFF + (size_t)b * DM + h * DV + d] = acc;
}

// ---------- Kernel D2: obase[b,:] = ctx[b,:] @ Wfc + bfc ----------
__global__ __launch_bounds__(512) void k_obase(const float* __restrict__ Wfc,
                                               const float* __restrict__ bfc,
                                               float* __restrict__ ws) {
    __shared__ float cx[DM];
    int b = blockIdx.x;
    cx[threadIdx.x] = ws[CTX_OFF + (size_t)b * DM + threadIdx.x];
    __syncthreads();
    int n = threadIdx.x;
    float acc = bfc[n];
#pragma unroll 4
    for (int m = 0; m < DM; ++m) acc += cx[m] * Wfc[(size_t)m * DM + n];
    ws[OB_OFF + (size_t)b * DM + n] = acc;
}

// ---------- Kernel E: out[b,l,:] = LN(q[b,l,:] + obase[b,:]) * scale + bias ----------
__global__ __launch_bounds__(256) void k_out(const float* __restrict__ q,
                                             const float* __restrict__ lns,
                                             const float* __restrict__ lnb,
                                             const float* __restrict__ ws,
                                             float* __restrict__ out) {
    int wave = threadIdx.x >> 6, lane = threadIdx.x & 63;
    int row = blockIdx.x * 4 + wave;  // b*L + l
    int b = row >> 10;
    const float* qr = q + (size_t)row * DM;
    const float* ob = ws + OB_OFF + (size_t)b * DM;
    int d0 = lane * 8;
    float4 a = *(const float4*)(qr + d0);
    float4 c = *(const float4*)(qr + d0 + 4);
    float4 oa = *(const float4*)(ob + d0);
    float4 oc = *(const float4*)(ob + d0 + 4);
    float x[8] = {a.x + oa.x, a.y + oa.y, a.z + oa.z, a.w + oa.w,
                  c.x + oc.x, c.y + oc.y, c.z + oc.z, c.w + oc.w};
    float sum = 0.f, sq = 0.f;
#pragma unroll
    for (int i = 0; i < 8; ++i) { sum += x[i]; sq += x[i] * x[i]; }
#pragma unroll
    for (int off = 32; off > 0; off >>= 1) {
        sum += __shfl_xor(sum, off, 64);
        sq  += __shfl_xor(sq,  off, 64);
    }
    float mu = sum * (1.f / DM);
    float var = sq * (1.f / DM) - mu * mu;
    float inv = rsqrtf(var + LN_EPS);
    float4 sa = *(const float4*)(lns + d0);
    float4 sc = *(const float4*)(lns + d0 + 4);
    float4 ba = *(const float4*)(lnb + d0);
    float4 bb = *(const float4*)(lnb + d0 + 4);
    float sarr[8] = {sa.x, sa.y, sa.z, sa.w, sc.x, sc.y, sc.z, sc.w};
    float barr[8] = {ba.x, ba.y, ba.z, ba.w, bb.x, bb.y, bb.z, bb.w};
    float y[8];
#pragma unroll
    for (int i = 0; i < 8; ++i) y[i] = (x[i] - mu) * inv * sarr[i] + barr[i];
    float4 o0 = {y[0], y[1], y[2], y[3]};
    float4 o1 = {y[4], y[5], y[6], y[7]};
    *(float4*)(out + (size_t)row * DM + d0) = o0;
    *(float4*)(out + (size_t)row * DM + d0 + 4) = o1;
}

// ---------- Kernel F: broadcast p rows into attn output (268 MB) ----------
__global__ __launch_bounds__(256) void k_attn(const float* __restrict__ ws,
                                              float* __restrict__ out) {
    int hb = blockIdx.x >> 6;       // 0..63
    int ic = blockIdx.x & 63;       // 16-row chunk
    float4 pv = *(const float4*)&ws[P_OFF + (size_t)hb * L + threadIdx.x * 4];
    float* base = out + OUT_ELEMS + ((size_t)hb * L + (size_t)ic * 16) * L + threadIdx.x * 4;
#pragma unroll
    for (int r = 0; r < 16; ++r)
        *(float4*)(base + (size_t)r * L) = pv;
}

extern "C" void kernel_launch(void* const* d_in, const int* in_sizes, int n_in,
                              void* d_out, int out_size, void* d_ws, size_t ws_size,
                              hipStream_t stream) {
    const float* q    = (const float*)d_in[0];
    const float* k    = (const float*)d_in[1];
    const float* v    = (const float*)d_in[2];
    // d_in[3]=Wq, d_in[4]=bq dead (cancel in softmax); d_in[10]=bmap dead
    const float* Wk   = (const float*)d_in[5];
    const float* bk   = (const float*)d_in[6];
    const float* Wv   = (const float*)d_in[7];
    const float* bv   = (const float*)d_in[8];
    const float* Wmap = (const float*)d_in[9];
    const float* Wfc  = (const float*)d_in[11];
    const float* bfc  = (const float*)d_in[12];
    const float* lns  = (const float*)d_in[13];
    const float* lnb  = (const float*)d_in[14];
    float* out = (float*)d_out;
    float* ws  = (float*)d_ws;

    hipLaunchKernelGGL(k_prep,    dim3(1),    dim3(512), 0, stream, Wk, bk, Wmap, ws);
    hipLaunchKernelGGL(k_sk,      dim3(2048), dim3(256), 0, stream, k, ws);
    hipLaunchKernelGGL(k_softmax, dim3(64),   dim3(256), 0, stream, ws);
    hipLaunchKernelGGL(k_vbar,    dim3(64),   dim3(512), 0, stream, v, ws);
    hipLaunchKernelGGL(k_ctx,     dim3(64),   dim3(64),  0, stream, Wv, bv, ws);
    hipLaunchKernelGGL(k_obase,   dim3(8),    dim3(512), 0, stream, Wfc, bfc, ws);
    hipLaunchKernelGGL(k_out,     dim3(2048), dim3(256), 0, stream, q, lns, lnb, ws, out);
    hipLaunchKernelGGL(k_attn,    dim3(4096), dim3(256), 0, stream, ws, out);
}

// Round 2
// 118.207 us; speedup vs baseline: 2.6618x; 2.6618x over previous
//
#include <hip/hip_runtime.h>
#include <cstdint>
#include <cstddef>

#define B 8
#define L 1024
#define DM 512
#define H 8
#define DK 64
#define DV 64
#define LN_EPS 1e-5f

// workspace layout (float offsets)
#define U_OFF    0        // DM*H = 4096        u[dm*8+h] = Wk[:,h*64:] @ wmap_k
#define CK_OFF   4096     // 8                  ck[h] = bk[h*64:] . wmap_k
#define SK_OFF   8192     // H*B*L = 65536      sk[(h*B+b)*L + l]
#define P_OFF    73728    // H*B*L = 65536      p (softmax rows)
#define PART_OFF 139264   // 4*H*B*DM = 131072  vbar partials [js][h][b][dm]
#define CTX_OFF  270336   // B*DM = 4096        ctxcat[b*DM + h*64+d]
#define OBP_OFF  274432   // 8*B*DM = 32768     obase partials [ms][b][n]

#define OUT_ELEMS  ((size_t)B * L * DM)      // 4194304, attn follows

typedef float f4 __attribute__((ext_vector_type(4)));

// ---------- A: u[dm,h] = Wk[dm, h*64:] . wmap_k ; ck[h] = bk[h*64:] . wmap_k ----------
// 64 blocks x 64 threads; block g covers dm in [g*8, g*8+8)
__global__ __launch_bounds__(64) void k_prep(const float* __restrict__ Wk,
                                             const float* __restrict__ bk,
                                             const float* __restrict__ Wmap,
                                             float* __restrict__ ws) {
    __shared__ float wm[DK];
    int t = threadIdx.x;
    wm[t] = Wmap[DK + t];
    __syncthreads();
    int h = t >> 3, part = t & 7;
#pragma unroll
    for (int i = 0; i < 8; ++i) {
        int dm = blockIdx.x * 8 + i;
        const float* row = Wk + (size_t)dm * (H * DK) + h * DK + part * 8;
        float s = 0.f;
#pragma unroll
        for (int d = 0; d < 8; ++d) s += row[d] * wm[part * 8 + d];
        s += __shfl_xor(s, 1, 64);
        s += __shfl_xor(s, 2, 64);
        s += __shfl_xor(s, 4, 64);
        if (part == 0) ws[U_OFF + dm * H + h] = s;
    }
    if (blockIdx.x == 0) {
        const float* rb = bk + h * DK + part * 8;
        float s = 0.f;
#pragma unroll
        for (int d = 0; d < 8; ++d) s += rb[d] * wm[part * 8 + d];
        s += __shfl_xor(s, 1, 64);
        s += __shfl_xor(s, 2, 64);
        s += __shfl_xor(s, 4, 64);
        if (part == 0) ws[CK_OFF + h] = s;
    }
}

// ---------- B: sk[h,b,l] = k[b,l,:] . u[:,h] + ck[h] ----------
__global__ __launch_bounds__(256) void k_sk(const float* __restrict__ k,
                                            float* __restrict__ ws) {
    int wave = threadIdx.x >> 6, lane = threadIdx.x & 63;
    int row = blockIdx.x * 4 + wave;  // b*L + l
    int b = row >> 10, l = row & 1023;
    const float* krow = k + (size_t)row * DM;
    const float* u = ws + U_OFF;
    float acc[8] = {0, 0, 0, 0, 0, 0, 0, 0};
#pragma unroll
    for (int s = 0; s < 8; ++s) {
        int dm = s * 64 + lane;
        float kv = krow[dm];
        const float4 ua = *(const float4*)(u + dm * 8);
        const float4 ub = *(const float4*)(u + dm * 8 + 4);
        acc[0] += kv * ua.x; acc[1] += kv * ua.y;
        acc[2] += kv * ua.z; acc[3] += kv * ua.w;
        acc[4] += kv * ub.x; acc[5] += kv * ub.y;
        acc[6] += kv * ub.z; acc[7] += kv * ub.w;
    }
#pragma unroll
    for (int off = 32; off > 0; off >>= 1) {
#pragma unroll
        for (int h = 0; h < 8; ++h) acc[h] += __shfl_xor(acc[h], off, 64);
    }
    float vout = 0.f;
#pragma unroll
    for (int h = 0; h < 8; ++h) if (lane == h) vout = acc[h];
    if (lane < 8)
        ws[SK_OFF + ((size_t)(lane * B + b)) * L + l] = vout + ws[CK_OFF + lane];
}

// ---------- C: p = softmax(sk) per (h,b) row ----------
__global__ __launch_bounds__(256) void k_softmax(float* __restrict__ ws) {
    int hb = blockIdx.x, t = threadIdx.x;
    int wave = t >> 6, lane = t & 63;
    const float4 s4 = *(const float4*)&ws[SK_OFF + (size_t)hb * L + t * 4];
    __shared__ float sred[4];
    __shared__ float bc[1];
    float m = fmaxf(fmaxf(s4.x, s4.y), fmaxf(s4.z, s4.w));
#pragma unroll
    for (int off = 32; off > 0; off >>= 1) m = fmaxf(m, __shfl_xor(m, off, 64));
    if (lane == 0) sred[wave] = m;
    __syncthreads();
    if (t == 0) bc[0] = fmaxf(fmaxf(sred[0], sred[1]), fmaxf(sred[2], sred[3]));
    __syncthreads();
    m = bc[0];
    float e0 = expf(s4.x - m), e1 = expf(s4.y - m), e2 = expf(s4.z - m), e3 = expf(s4.w - m);
    float s = e0 + e1 + e2 + e3;
#pragma unroll
    for (int off = 32; off > 0; off >>= 1) s += __shfl_xor(s, off, 64);
    __syncthreads();
    if (lane == 0) sred[wave] = s;
    __syncthreads();
    if (t == 0) bc[0] = sred[0] + sred[1] + sred[2] + sred[3];
    __syncthreads();
    float inv = 1.f / bc[0];
    float4 p4 = {e0 * inv, e1 * inv, e2 * inv, e3 * inv};
    *(float4*)&ws[P_OFF + (size_t)hb * L + t * 4] = p4;
}

// ---------- C2: vbar partials over j-segments of 256 ----------
// grid 256 = (js 0..3, b 0..7, chunk 0..7); 512 threads = (h wave, dml lane)
__global__ __launch_bounds__(512) void k_vbar(const float* __restrict__ v,
                                              float* __restrict__ ws) {
    __shared__ float ps[H * 256];  // 8 KB
    int blk = blockIdx.x;
    int chunk = blk & 7, b = (blk >> 3) & 7, js = blk >> 6;
    for (int idx = threadIdx.x; idx < H * 256; idx += 512) {
        int hh = idx >> 8, jj = idx & 255;
        ps[idx] = ws[P_OFF + ((size_t)(hh * B + b)) * L + js * 256 + jj];
    }
    __syncthreads();
    int h = threadIdx.x >> 6, dml = threadIdx.x & 63;
    int dm = chunk * 64 + dml;
    const float* vb0 = v + ((size_t)b * L + js * 256) * DM + dm;
    const float* ph = &ps[h * 256];
    float acc = 0.f;
#pragma unroll 4
    for (int jj = 0; jj < 256; ++jj) acc += ph[jj] * vb0[(size_t)jj * DM];
    ws[PART_OFF + ((size_t)((js * H + h) * B + b)) * DM + dm] = acc;
}

// ---------- D1: ctx[b, h*64+d] = vbar[h,b,:] @ Wv[:, h*64+d] + bv ----------
// grid 64 (hb), 256 threads = 4 waves splitting the dm loop
__global__ __launch_bounds__(256) void k_ctx(const float* __restrict__ Wv,
                                             const float* __restrict__ bv,
                                             float* __restrict__ ws) {
    __shared__ float vb[DM];
    __shared__ float red[4][64];
    int hb = blockIdx.x;
    int h = hb >> 3, b = hb & 7;
#pragma unroll
    for (int it = 0; it < 2; ++it) {
        int dm = threadIdx.x + it * 256;
        float s = 0.f;
#pragma unroll
        for (int js = 0; js < 4; ++js)
            s += ws[PART_OFF + ((size_t)((js * H + h) * B + b)) * DM + dm];
        vb[dm] = s;
    }
    __syncthreads();
    int w = threadIdx.x >> 6, d = threadIdx.x & 63;
    float acc = 0.f;
#pragma unroll 4
    for (int i = 0; i < 128; ++i) {
        int dm = w * 128 + i;
        acc += vb[dm] * Wv[(size_t)dm * (H * DV) + h * DV + d];
    }
    red[w][d] = acc;
    __syncthreads();
    if (w == 0) {
        float r = red[0][d] + red[1][d] + red[2][d] + red[3][d] + bv[h * DV + d];
        ws[CTX_OFF + (size_t)b * DM + h * DV + d] = r;
    }
}

// ---------- D2: obase partials over m-segments of 64 ----------
// grid 64 = (ms 0..7, b 0..7); 512 threads (one per n)
__global__ __launch_bounds__(512) void k_obase(const float* __restrict__ Wfc,
                                               float* __restrict__ ws) {
    __shared__ float cxs[64];
    int b = blockIdx.x & 7, ms = blockIdx.x >> 3;
    if (threadIdx.x < 64)
        cxs[threadIdx.x] = ws[CTX_OFF + (size_t)b * DM + ms * 64 + threadIdx.x];
    __syncthreads();
    int n = threadIdx.x;
    float acc = 0.f;
#pragma unroll 4
    for (int m = 0; m < 64; ++m)
        acc += cxs[m] * Wfc[(size_t)(ms * 64 + m) * DM + n];
    ws[OBP_OFF + (size_t)(ms * B + b) * DM + n] = acc;
}

// ---------- E: out[b,l,:] = LN(q[b,l,:] + obase[b,:]) ----------
__global__ __launch_bounds__(256) void k_out(const float* __restrict__ q,
                                             const float* __restrict__ bfc,
                                             const float* __restrict__ lns,
                                             const float* __restrict__ lnb,
                                             const float* __restrict__ ws,
                                             float* __restrict__ out) {
    __shared__ float obf[DM];
    int b = blockIdx.x >> 8;  // 256 blocks per batch
    for (int i = threadIdx.x; i < DM; i += 256) {
        float s = bfc[i];
#pragma unroll
        for (int ms = 0; ms < 8; ++ms)
            s += ws[OBP_OFF + (size_t)(ms * B + b) * DM + i];
        obf[i] = s;
    }
    __syncthreads();
    int wave = threadIdx.x >> 6, lane = threadIdx.x & 63;
    int row = blockIdx.x * 4 + wave;
    const float* qr = q + (size_t)row * DM;
    int d0 = lane * 8;
    float4 a = *(const float4*)(qr + d0);
    float4 c = *(const float4*)(qr + d0 + 4);
    float x[8] = {a.x + obf[d0], a.y + obf[d0 + 1], a.z + obf[d0 + 2], a.w + obf[d0 + 3],
                  c.x + obf[d0 + 4], c.y + obf[d0 + 5], c.z + obf[d0 + 6], c.w + obf[d0 + 7]};
    float sum = 0.f, sq = 0.f;
#pragma unroll
    for (int i = 0; i < 8; ++i) { sum += x[i]; sq += x[i] * x[i]; }
#pragma unroll
    for (int off = 32; off > 0; off >>= 1) {
        sum += __shfl_xor(sum, off, 64);
        sq  += __shfl_xor(sq,  off, 64);
    }
    float mu = sum * (1.f / DM);
    float var = sq * (1.f / DM) - mu * mu;
    float inv = rsqrtf(var + LN_EPS);
    float4 sa = *(const float4*)(lns + d0);
    float4 sc = *(const float4*)(lns + d0 + 4);
    float4 ba = *(const float4*)(lnb + d0);
    float4 bb = *(const float4*)(lnb + d0 + 4);
    float sarr[8] = {sa.x, sa.y, sa.z, sa.w, sc.x, sc.y, sc.z, sc.w};
    float barr[8] = {ba.x, ba.y, ba.z, ba.w, bb.x, bb.y, bb.z, bb.w};
    float y[8];
#pragma unroll
    for (int i = 0; i < 8; ++i) y[i] = (x[i] - mu) * inv * sarr[i] + barr[i];
    float4 o0 = {y[0], y[1], y[2], y[3]};
    float4 o1 = {y[4], y[5], y[6], y[7]};
    *(float4*)(out + (size_t)row * DM + d0) = o0;
    *(float4*)(out + (size_t)row * DM + d0 + 4) = o1;
}

// ---------- F: broadcast p rows into attn output (268 MB, streaming) ----------
__global__ __launch_bounds__(256) void k_attn(const float* __restrict__ ws,
                                              float* __restrict__ out) {
    int hb = blockIdx.x >> 6;
    int ic = blockIdx.x & 63;
    f4 pv = *(const f4*)&ws[P_OFF + (size_t)hb * L + threadIdx.x * 4];
    float* base = out + OUT_ELEMS + ((size_t)hb * L + (size_t)ic * 16) * L + threadIdx.x * 4;
#pragma unroll
    for (int r = 0; r < 16; ++r)
        __builtin_nontemporal_store(pv, (f4*)(base + (size_t)r * L));
}

extern "C" void kernel_launch(void* const* d_in, const int* in_sizes, int n_in,
                              void* d_out, int out_size, void* d_ws, size_t ws_size,
                              hipStream_t stream) {
    const float* q    = (const float*)d_in[0];
    const float* k    = (const float*)d_in[1];
    const float* v    = (const float*)d_in[2];
    // d_in[3]=Wq, d_in[4]=bq dead (cancel in softmax); d_in[10]=bmap dead
    const float* Wk   = (const float*)d_in[5];
    const float* bk   = (const float*)d_in[6];
    const float* Wv   = (const float*)d_in[7];
    const float* bv   = (const float*)d_in[8];
    const float* Wmap = (const float*)d_in[9];
    const float* Wfc  = (const float*)d_in[11];
    const float* bfc  = (const float*)d_in[12];
    const float* lns  = (const float*)d_in[13];
    const float* lnb  = (const float*)d_in[14];
    float* out = (float*)d_out;
    float* ws  = (float*)d_ws;

    hipLaunchKernelGGL(k_prep,    dim3(64),   dim3(64),  0, stream, Wk, bk, Wmap, ws);
    hipLaunchKernelGGL(k_sk,      dim3(2048), dim3(256), 0, stream, k, ws);
    hipLaunchKernelGGL(k_softmax, dim3(64),   dim3(256), 0, stream, ws);
    hipLaunchKernelGGL(k_vbar,    dim3(256),  dim3(512), 0, stream, v, ws);
    hipLaunchKernelGGL(k_ctx,     dim3(64),   dim3(256), 0, stream, Wv, bv, ws);
    hipLaunchKernelGGL(k_obase,   dim3(64),   dim3(512), 0, stream, Wfc, ws);
    hipLaunchKernelGGL(k_out,     dim3(2048), dim3(256), 0, stream, q, bfc, lns, lnb, ws, out);
    hipLaunchKernelGGL(k_attn,    dim3(4096), dim3(256), 0, stream, ws, out);
}